// Round 9
// baseline (823.892 us; speedup 1.0000x reference)
//
#include <hip/hip_runtime.h>

typedef unsigned short u16;
typedef float f32x4 __attribute__((ext_vector_type(4)));
typedef short short8 __attribute__((ext_vector_type(8)));

#define C_ 2048
#define L_ 2048
#define H_ 16
#define D_ 128
#define SIXC 12288

__device__ __forceinline__ u16 f2bf(float f) {
  union { float f; unsigned u; } v; v.f = f;
  unsigned r = v.u + 0x7FFFu + ((v.u >> 16) & 1u);
  return (u16)(r >> 16);
}
__device__ __forceinline__ float bf2f(u16 b) {
  union { unsigned u; float f; } v; v.u = ((unsigned)b) << 16; return v.f;
}

#define GLOAD_LDS16(g, l)                                            \
  __builtin_amdgcn_global_load_lds(                                  \
      (__attribute__((address_space(1))) void*)(g),                  \
      (__attribute__((address_space(3))) void*)(l), 16, 0, 0)

template <int N> __device__ __forceinline__ void wait_vmcnt() {
  if constexpr (N == 8)      asm volatile("s_waitcnt vmcnt(8)" ::: "memory");
  else if constexpr (N == 6) asm volatile("s_waitcnt vmcnt(6)" ::: "memory");
  else if constexpr (N == 4) asm volatile("s_waitcnt vmcnt(4)" ::: "memory");
  else                       asm volatile("s_waitcnt vmcnt(0)" ::: "memory");
}

// ---------------- convert all 4 weight mats f32 -> bf16 (one launch) --------
#define NQKV 12582912
#define NPRJ 4194304
#define NFC1 16777216
#define NFC2 16777216
__global__ __launch_bounds__(256) void conv_all(
    const float* __restrict__ wqkv, const float* __restrict__ wproj,
    const float* __restrict__ wfc1, const float* __restrict__ wfc2,
    u16* __restrict__ oqkv, u16* __restrict__ oproj,
    u16* __restrict__ ofc1, u16* __restrict__ ofc2) {
  int i = (blockIdx.x * 256 + threadIdx.x) * 4;
  const float* src; u16* dst; int off;
  if (i < NQKV) { src = wqkv; dst = oqkv; off = i; }
  else if (i < NQKV + NPRJ) { src = wproj; dst = oproj; off = i - NQKV; }
  else if (i < NQKV + NPRJ + NFC1) { src = wfc1; dst = ofc1; off = i - NQKV - NPRJ; }
  else { src = wfc2; dst = ofc2; off = i - NQKV - NPRJ - NFC1; }
  float4 v = *(const float4*)&src[off];
  ushort4 o;
  o.x = f2bf(v.x); o.y = f2bf(v.y); o.z = f2bf(v.z); o.w = f2bf(v.w);
  *(ushort4*)&dst[off] = o;
}

// ---------------- prep: silu(cond), qkv bias, per-head scale, zero flag -----
__global__ __launch_bounds__(256) void prep_kernel(
    const float* __restrict__ cond, const float* __restrict__ qb,
    const float* __restrict__ vb, const float* __restrict__ sml,
    float* __restrict__ silu_cond, float* __restrict__ qkvbias,
    float* __restrict__ sm, int* __restrict__ bflag) {
  int i = blockIdx.x * 256 + threadIdx.x;
  if (i == 0) bflag[0] = 0;
  if (i < 4096) { float c = cond[i]; silu_cond[i] = c / (1.f + __expf(-c)); }
  if (i < 6144) {
    float bv = (i < 2048) ? qb[i] : ((i < 4096) ? 0.f : vb[i - 4096]);
    qkvbias[i] = bv;
  }
  if (i < 16) sm[i] = __expf(fminf(sml[i], 4.6051701859880914f)); // log(100)
}

// ---------------- attn_bias zero detect (16MB scan) -------------------------
__global__ __launch_bounds__(256) void bias_check(
    const float* __restrict__ b, int* __restrict__ flag) {
  int i = (blockIdx.x * 256 + threadIdx.x) * 4;
  float4 v = *(const float4*)&b[i];
  bool nz = (v.x != 0.f) | (v.y != 0.f) | (v.z != 0.f) | (v.w != 0.f);
  if (__any(nz) && (threadIdx.x & 63) == 0) atomicOr(flag, 1);
}

// ---------------- ada = silu(cond) @ Wada^T + bada  (one wave per row) ------
__global__ __launch_bounds__(256) void ada_gemm(
    const float* __restrict__ sc, const float* __restrict__ Wada,
    const float* __restrict__ bada, float* __restrict__ ada) {
  int gw = (blockIdx.x * 256 + threadIdx.x) >> 6;
  int lane = threadIdx.x & 63;
  int b = gw / SIXC, row = gw % SIXC;
  const float* s0 = sc + b * 2048;
  const float* w0 = Wada + (size_t)row * 2048;
  float s = 0.f;
  for (int k = lane * 4; k < 2048; k += 256) {
    float4 a = *(const float4*)&s0[k];
    float4 w = *(const float4*)&w0[k];
    s = fmaf(a.x, w.x, s); s = fmaf(a.y, w.y, s);
    s = fmaf(a.z, w.z, s); s = fmaf(a.w, w.w, s);
  }
  #pragma unroll
  for (int off = 32; off; off >>= 1) s += __shfl_xor(s, off);
  if (lane == 0) ada[(size_t)b * SIXC + row] = s + bada[row];
}

// ---------------- LN + modulate -> bf16 -------------------------------------
__global__ __launch_bounds__(256) void ln_mod(
    const float* __restrict__ x, const float* __restrict__ ada,
    u16* __restrict__ out, int soff, int shoff) {
  int r = blockIdx.x;            // row in [0,4096)
  int b = r >> 11;
  int tid = threadIdx.x;
  const float* xr = x + (size_t)r * 2048;
  int c0 = tid * 8;
  float4 u0 = *(const float4*)&xr[c0];
  float4 u1 = *(const float4*)&xr[c0 + 4];
  float v[8] = {u0.x,u0.y,u0.z,u0.w,u1.x,u1.y,u1.z,u1.w};
  float s = 0.f, s2 = 0.f;
  #pragma unroll
  for (int j = 0; j < 8; ++j) { s += v[j]; s2 = fmaf(v[j], v[j], s2); }
  int wv = tid >> 6, lane = tid & 63;
  #pragma unroll
  for (int off = 32; off; off >>= 1) { s += __shfl_xor(s, off); s2 += __shfl_xor(s2, off); }
  __shared__ float red[8];
  if (!lane) { red[wv] = s; red[4 + wv] = s2; }
  __syncthreads();
  s = red[0] + red[1] + red[2] + red[3];
  s2 = red[4] + red[5] + red[6] + red[7];
  float mean = s * (1.f / 2048.f);
  float var = s2 * (1.f / 2048.f) - mean * mean;
  float rstd = rsqrtf(var + 1e-6f);
  const float* sc = ada + (size_t)b * SIXC + soff;
  const float* sh = ada + (size_t)b * SIXC + shoff;
  u16* orow = out + (size_t)r * 2048;
  #pragma unroll
  for (int j = 0; j < 8; ++j) {
    int c = c0 + j;
    float y = (v[j] - mean) * rstd * (1.f + sc[c]) + sh[c];
    orow[c] = f2bf(y);
  }
}

// ---------------- q/k L2 normalize in place (bf16), q *= sm[h] --------------
__global__ __launch_bounds__(256) void qk_norm_bf(
    u16* __restrict__ qb, u16* __restrict__ kb, const float* __restrict__ sm) {
  int gw = (blockIdx.x * 256 + threadIdx.x) >> 6;  // [0, 131072)
  int lane = threadIdx.x & 63;
  int which = gw >> 16;         // 0: q, 1: k (65536 rows each)
  int rid = gw & 0xFFFF;
  int h = (rid >> 11) & 15;
  u16* base = (which ? kb : qb) + (size_t)rid * 128 + lane * 2;
  unsigned uu = *(const unsigned*)base;
  float v0 = bf2f((u16)(uu & 0xFFFFu));
  float v1 = bf2f((u16)(uu >> 16));
  float ss = v0 * v0 + v1 * v1;
  #pragma unroll
  for (int off = 32; off; off >>= 1) ss += __shfl_xor(ss, off);
  float rn = 1.f / fmaxf(sqrtf(ss), 1e-12f);
  if (which == 0) rn *= sm[h];
  unsigned o = (unsigned)f2bf(v0 * rn) | ((unsigned)f2bf(v1 * rn) << 16);
  *(unsigned*)base = o;
}

// -- MFMA flash attention (v5 + zero-bias fast path) -------------------------
#define PSP 68
__global__ __launch_bounds__(256) void attn_mfma(
    const u16* __restrict__ qb, const u16* __restrict__ kb,
    const u16* __restrict__ vbt, const float* __restrict__ bias,
    const int* __restrict__ bflag, u16* __restrict__ o) {
  __shared__ u16 Ks[2][64 * 128];
  __shared__ u16 Vt[2][128 * 64];
  __shared__ u16 Ps[4][16 * PSP];
  int tid = threadIdx.x;
  int w = tid >> 6, lane = tid & 63;
  int flat = blockIdx.y * gridDim.x + blockIdx.x;
  int rl = (flat & 7) * 128 + (flat >> 3);
  int bh = rl >> 5, b = bh >> 4, h = bh & 15;
  int q0 = (rl & 31) * 64;
  int lr = lane & 15, lg = lane >> 4;
  const int hasb = bflag[0];
  short8 aq[4];
  {
    const u16* qrow = qb + ((size_t)bh * L_ + q0 + w * 16 + lr) * 128 + lg * 8;
    #pragma unroll
    for (int ks = 0; ks < 4; ++ks) aq[ks] = *(const short8*)(qrow + ks * 32);
  }
  f32x4 oacc[8] = {};
  float m = -1e30f, l = 0.f;
  const float* brow = bias + (size_t)(q0 + w * 16 + lr) * L_;
  const u16* kbase = kb + (size_t)bh * L_ * 128;
  const u16* vbase = vbt + (size_t)bh * 128 * L_;
  const int kq0 = tid;
  const int vq0 = tid;

  float4 brg[4], bnr[4];
  #pragma unroll
  for (int i = 0; i < 4; ++i) {
    int q = i * 256 + kq0;
    int r = q >> 4, c = q & 15;
    GLOAD_LDS16(kbase + (size_t)r * 128 + ((c ^ (r & 7)) * 8), &Ks[0][q * 8]);
  }
  #pragma unroll
  for (int i = 0; i < 4; ++i) {
    int q = i * 256 + vq0;
    int r = q >> 3, c = q & 7;
    GLOAD_LDS16(vbase + (size_t)r * L_ + ((c ^ (r & 7)) * 8), &Vt[0][q * 8]);
  }
  #pragma unroll
  for (int kg = 0; kg < 4; ++kg) {
    if (hasb) brg[kg] = *(const float4*)&brow[kg * 16 + lg * 4];
    else { brg[kg].x = 0.f; brg[kg].y = 0.f; brg[kg].z = 0.f; brg[kg].w = 0.f; }
    bnr[kg].x = 0.f; bnr[kg].y = 0.f; bnr[kg].z = 0.f; bnr[kg].w = 0.f;
  }
  __syncthreads();

  for (int kt = 0; kt < 32; ++kt) {
    const int cur = kt & 1;
    if (kt < 31) {
      const int nxt = cur ^ 1;
      const u16* kb2 = kbase + (size_t)(kt + 1) * 64 * 128;
      #pragma unroll
      for (int i = 0; i < 4; ++i) {
        int q = i * 256 + kq0;
        int r = q >> 4, c = q & 15;
        GLOAD_LDS16(kb2 + (size_t)r * 128 + ((c ^ (r & 7)) * 8), &Ks[nxt][q * 8]);
      }
      #pragma unroll
      for (int i = 0; i < 4; ++i) {
        int q = i * 256 + vq0;
        int r = q >> 3, c = q & 7;
        GLOAD_LDS16(vbase + (size_t)r * L_ + (kt + 1) * 64 + ((c ^ (r & 7)) * 8),
                    &Vt[nxt][q * 8]);
      }
      if (hasb) {
        #pragma unroll
        for (int kg = 0; kg < 4; ++kg)
          bnr[kg] = *(const float4*)&brow[(kt + 1) * 64 + kg * 16 + lg * 4];
      }
    }
    f32x4 s[4] = {};
    __builtin_amdgcn_s_setprio(1);
    #pragma unroll
    for (int ks = 0; ks < 4; ++ks) {
      #pragma unroll
      for (int kg = 0; kg < 4; ++kg) {
        int row = kg * 16 + lr;
        short8 bk = *(const short8*)&Ks[cur][row * 128 + (((ks * 4 + lg) ^ (lr & 7)) * 8)];
        s[kg] = __builtin_amdgcn_mfma_f32_16x16x32_bf16(bk, aq[ks], s[kg], 0, 0, 0);
      }
    }
    __builtin_amdgcn_s_setprio(0);
    float p[4][4];
    #pragma unroll
    for (int kg = 0; kg < 4; ++kg) {
      p[kg][0] = s[kg][0] + brg[kg].x;
      p[kg][1] = s[kg][1] + brg[kg].y;
      p[kg][2] = s[kg][2] + brg[kg].z;
      p[kg][3] = s[kg][3] + brg[kg].w;
    }
    float tm = fmaxf(
        fmaxf(fmaxf(fmaxf(p[0][0], p[0][1]), fmaxf(p[0][2], p[0][3])),
              fmaxf(fmaxf(p[1][0], p[1][1]), fmaxf(p[1][2], p[1][3]))),
        fmaxf(fmaxf(fmaxf(p[2][0], p[2][1]), fmaxf(p[2][2], p[2][3])),
              fmaxf(fmaxf(p[3][0], p[3][1]), fmaxf(p[3][2], p[3][3]))));
    tm = fmaxf(tm, __shfl_xor(tm, 16));
    tm = fmaxf(tm, __shfl_xor(tm, 32));
    if (__any(tm > m + 8.f)) {
      float nm = fmaxf(m, tm);
      float a = __expf(m - nm);
      m = nm;
      l *= a;
      float al[4];
      #pragma unroll
      for (int j = 0; j < 4; ++j) al[j] = __shfl(a, lg * 4 + j);
      #pragma unroll
      for (int dg = 0; dg < 8; ++dg) {
        f32x4 t = oacc[dg];
        t[0] *= al[0]; t[1] *= al[1]; t[2] *= al[2]; t[3] *= al[3];
        oacc[dg] = t;
      }
    }
    float ps = 0.f;
    #pragma unroll
    for (int kg = 0; kg < 4; ++kg) {
      #pragma unroll
      for (int j = 0; j < 4; ++j) { p[kg][j] = __expf(p[kg][j] - m); ps += p[kg][j]; }
    }
    ps += __shfl_xor(ps, 16);
    ps += __shfl_xor(ps, 32);
    l += ps;
    #pragma unroll
    for (int kg = 0; kg < 4; ++kg) {
      unsigned lo = (unsigned)f2bf(p[kg][0]) | ((unsigned)f2bf(p[kg][1]) << 16);
      unsigned hi = (unsigned)f2bf(p[kg][2]) | ((unsigned)f2bf(p[kg][3]) << 16);
      uint2 w2; w2.x = lo; w2.y = hi;
      *(uint2*)&Ps[w][lr * PSP + kg * 16 + lg * 4] = w2;
    }
    __threadfence_block();
    short8 pa0 = *(const short8*)&Ps[w][lr * PSP + lg * 8];
    short8 pa1 = *(const short8*)&Ps[w][lr * PSP + 32 + lg * 8];
    __builtin_amdgcn_s_setprio(1);
    #pragma unroll
    for (int dg = 0; dg < 8; ++dg) {
      int row = dg * 16 + lr;
      short8 bv0 = *(const short8*)&Vt[cur][row * 64 + ((lg ^ (lr & 7)) * 8)];
      oacc[dg] = __builtin_amdgcn_mfma_f32_16x16x32_bf16(pa0, bv0, oacc[dg], 0, 0, 0);
      short8 bv1 = *(const short8*)&Vt[cur][row * 64 + (((4 + lg) ^ (lr & 7)) * 8)];
      oacc[dg] = __builtin_amdgcn_mfma_f32_16x16x32_bf16(pa1, bv1, oacc[dg], 0, 0, 0);
    }
    __builtin_amdgcn_s_setprio(0);
    __syncthreads();
    #pragma unroll
    for (int i = 0; i < 4; ++i) brg[i] = bnr[i];
  }
  float inv[4];
  #pragma unroll
  for (int j = 0; j < 4; ++j) inv[j] = 1.f / __shfl(l, lg * 4 + j);
  #pragma unroll
  for (int j = 0; j < 4; ++j) {
    u16* dst = &o[((size_t)(b * L_) + q0 + w * 16 + lg * 4 + j) * 2048 + h * 128 + lr];
    #pragma unroll
    for (int dg = 0; dg < 8; ++dg) dst[dg * 16] = f2bf(oacc[dg][j] * inv[j]);
  }
}

// ------ 128x128 bf16 GEMM, BK=32, 32KB LDS -> 3 blocks/CU (12 waves) --------
// Occupancy lever: unified VGPR(88)+AGPR(64)=152 <= 170 allows 3 waves/SIMD;
// LDS 32KB allows 3+ blocks/CU. Cross-block overlap (m114) fills barrier
// bubbles. Counted-vmcnt double buffer as R3.
// Bank swizzle (row stride 64B = 16 banks): LDS slot s of row r holds global
// slot s^((r>>1)&3); read col = (lg^((lr>>1)&3))*8. Same-parity rows fold
// 2-way (free); even/odd rows are bank-phase disjoint.
// EPI 0: qkv scatter; EPI 1: gelu->bf16; EPI 2: f32 out = res+(acc+b)*ada
template <int EPI>
__global__ __launch_bounds__(256, 3) void gemm128(
    const u16* __restrict__ A, const u16* __restrict__ W,
    const float* __restrict__ bias, const float* __restrict__ res,
    const float* __restrict__ ada, int goff,
    float* __restrict__ outf, u16* __restrict__ outb,
    u16* __restrict__ p0, u16* __restrict__ p1, u16* __restrict__ p2,
    int M, int N, int K) {
  __shared__ __attribute__((aligned(16))) u16 As[2][128 * 32];
  __shared__ __attribute__((aligned(16))) u16 Bs[2][128 * 32];
  const int tid = threadIdx.x;
  const int m0 = blockIdx.y * 128, n0 = blockIdx.x * 128;
  const int wv = tid >> 6, lane = tid & 63;
  const int wr = wv >> 1, wc = wv & 1;
  const int lr = lane & 15, lg = lane >> 4;
  // staging: lane l -> row l>>2, slot l&3 within a 16-row chunk (1KB/wave-op)
  const int srow = lane >> 2;
  const int scol = ((lane & 3) ^ ((lane >> 3) & 3)) * 8;  // pre-swz source col
  const int cswz = (lr >> 1) & 3;                          // read-side slot xor
  f32x4 acc[4][4] = {};
  const u16* Ab = A + (size_t)m0 * K;
  const u16* Bb = W + (size_t)n0 * K;
  const int nt = K >> 5;
  auto stage = [&](int bi, int k0) {
    #pragma unroll
    for (int p = 0; p < 2; ++p) {
      int chunk = wv * 2 + p;                // 8 chunks x 16 rows = 128
      int row = chunk * 16 + srow;
      GLOAD_LDS16(Ab + (size_t)row * K + k0 + scol, &As[bi][chunk * 512]);
      GLOAD_LDS16(Bb + (size_t)row * K + k0 + scol, &Bs[bi][chunk * 512]);
    }
  };
  // prologue: tiles 0 and 1 in flight (8 loads)
  stage(0, 0);
  stage(1, 32);
  for (int t = 0; t < nt; ++t) {
    const int cur = t & 1;
    if (t + 1 < nt) wait_vmcnt<4>(); else wait_vmcnt<0>();
    __builtin_amdgcn_s_barrier();          // buf[cur] staged for all waves
    __builtin_amdgcn_sched_barrier(0);     // reads stay below the barrier
    short8 af[4], bfr[4];
    const int col = (lg ^ cswz) * 8;
    #pragma unroll
    for (int i = 0; i < 4; ++i) {
      af[i]  = *(const short8*)&As[cur][(wr * 64 + i * 16 + lr) * 32 + col];
      bfr[i] = *(const short8*)&Bs[cur][(wc * 64 + i * 16 + lr) * 32 + col];
    }
    #pragma unroll
    for (int mi = 0; mi < 4; ++mi)
      #pragma unroll
      for (int ni = 0; ni < 4; ++ni)
        acc[mi][ni] = __builtin_amdgcn_mfma_f32_16x16x32_bf16(af[mi], bfr[ni], acc[mi][ni], 0, 0, 0);
    __builtin_amdgcn_sched_barrier(0);
    asm volatile("s_waitcnt lgkmcnt(0)" ::: "memory");  // my buf[cur] reads done
    __builtin_amdgcn_s_barrier();          // all waves' reads done -> cur free
    __builtin_amdgcn_sched_barrier(0);     // staging stays below
    if (t + 2 < nt) stage(cur, (t + 2) << 5);
  }
  #pragma unroll
  for (int mi = 0; mi < 4; ++mi) {
    #pragma unroll
    for (int ni = 0; ni < 4; ++ni) {
      int gcol = n0 + wc * 64 + ni * 16 + lr;
      float bv = bias[gcol];
      #pragma unroll
      for (int j = 0; j < 4; ++j) {
        int grow = m0 + wr * 64 + mi * 16 + lg * 4 + j;
        float v = acc[mi][ni][j] + bv;
        if constexpr (EPI == 0) {
          int which = gcol >> 11;
          int h = (gcol >> 7) & 15;
          int d = gcol & 127;
          int b = grow >> 11, ll = grow & 2047;
          int bh = b * 16 + h;
          if (which == 0)      p0[((size_t)bh * L_ + ll) * 128 + d] = f2bf(v);
          else if (which == 1) p1[((size_t)bh * L_ + ll) * 128 + d] = f2bf(v);
          else                 p2[((size_t)bh * 128 + d) * L_ + ll] = f2bf(v);
        } else if constexpr (EPI == 1) {
          float u = 0.7978845608028654f * (v + 0.044715f * v * v * v);
          float e = __expf(2.f * u);
          float th = 1.f - 2.f / (e + 1.f);
          outb[(size_t)grow * N + gcol] = f2bf(0.5f * v * (1.f + th));
        } else {
          int b = grow >> 11;
          float g = ada[(size_t)b * SIXC + goff + gcol];
          size_t oi = (size_t)grow * N + gcol;
          outf[oi] = res[oi] + v * g;
        }
      }
    }
  }
}

// ---------------------------------------------------------------------------
extern "C" void kernel_launch(void* const* d_in, const int* in_sizes, int n_in,
                              void* d_out, int out_size, void* d_ws, size_t ws_size,
                              hipStream_t stream) {
  const float* x        = (const float*)d_in[0];
  const float* cond     = (const float*)d_in[1];
  const float* attnbias = (const float*)d_in[2];
  const float* Wqkv     = (const float*)d_in[3];
  const float* q_bias   = (const float*)d_in[4];
  const float* v_bias   = (const float*)d_in[5];
  const float* sml      = (const float*)d_in[6];
  const float* Wproj    = (const float*)d_in[7];
  const float* bproj    = (const float*)d_in[8];
  const float* Wada     = (const float*)d_in[9];
  const float* bada     = (const float*)d_in[10];
  const float* Wfc1     = (const float*)d_in[11];
  const float* bfc1     = (const float*)d_in[12];
  const float* Wfc2     = (const float*)d_in[13];
  const float* bfc2     = (const float*)d_in[14];
  float* out = (float*)d_out;
  char* ws = (char*)d_ws;
  const size_t MB = 1ull << 20;

  float* silu_cond = (float*)(ws + 0);
  float* qkvbias   = (float*)(ws + (16 << 10));
  float* smbuf     = (float*)(ws + (40 << 10));
  int*   bflag     = (int*)(ws + (44 << 10));
  float* adab      = (float*)(ws + (48 << 10));
  u16*   xob       = (u16*)(ws + 1 * MB);     // 16MB: ln1 out / attn out / ln2 out
  u16*   qbb       = (u16*)(ws + 17 * MB);    // 16MB
  u16*   kbb       = (u16*)(ws + 33 * MB);    // 16MB
  float* x1        = (float*)(ws + 17 * MB);  // 32MB f32 (aliases qbb+kbb, dead by proj)
  u16*   vbt       = (u16*)(ws + 49 * MB);    // 16MB
  u16*   hbuf      = (u16*)(ws + 49 * MB);    // 64MB (aliases vbt+wqkv+wproj, dead by fc1)
  u16*   wqkv_bf   = (u16*)(ws + 65 * MB);    // 24MB
  u16*   wproj_bf  = (u16*)(ws + 89 * MB);    // 8MB
  u16*   wfc1_bf   = (u16*)(ws + 113 * MB);   // 32MB
  u16*   wfc2_bf   = (u16*)(ws + 145 * MB);   // 32MB  (total 177MB)

  conv_all<<<49152, 256, 0, stream>>>(Wqkv, Wproj, Wfc1, Wfc2,
                                      wqkv_bf, wproj_bf, wfc1_bf, wfc2_bf);
  prep_kernel<<<24, 256, 0, stream>>>(cond, q_bias, v_bias, sml, silu_cond,
                                      qkvbias, smbuf, bflag);
  bias_check<<<4096, 256, 0, stream>>>(attnbias, bflag);
  ada_gemm<<<6144, 256, 0, stream>>>(silu_cond, Wada, bada, adab);
  ln_mod<<<4096, 256, 0, stream>>>(x, adab, xob, 2 * C_, 4 * C_);
  gemm128<0><<<dim3(48, 32), 256, 0, stream>>>(xob, wqkv_bf, qkvbias, nullptr, nullptr, 0,
      nullptr, nullptr, qbb, kbb, vbt, 4096, 6144, 2048);
  qk_norm_bf<<<32768, 256, 0, stream>>>(qbb, kbb, smbuf);
  attn_mfma<<<dim3(32, 32), 256, 0, stream>>>(qbb, kbb, vbt, attnbias, bflag, xob);
  gemm128<2><<<dim3(16, 32), 256, 0, stream>>>(xob, wproj_bf, bproj, x, adab, 0,
      x1, nullptr, nullptr, nullptr, nullptr, 4096, 2048, 2048);
  ln_mod<<<4096, 256, 0, stream>>>(x1, adab, xob, 3 * C_, 5 * C_);
  gemm128<1><<<dim3(64, 32), 256, 0, stream>>>(xob, wfc1_bf, bfc1, nullptr, nullptr, 0,
      nullptr, hbuf, nullptr, nullptr, nullptr, 4096, 8192, 2048);
  gemm128<2><<<dim3(16, 32), 256, 0, stream>>>(hbuf, wfc2_bf, bfc2, x1, adab, C_,
      out, nullptr, nullptr, nullptr, nullptr, 4096, 2048, 8192);
}

// Round 11
// 768.557 us; speedup vs baseline: 1.0720x; 1.0720x over previous
//
#include <hip/hip_runtime.h>

typedef unsigned short u16;
typedef float f32x4 __attribute__((ext_vector_type(4)));
typedef short short8 __attribute__((ext_vector_type(8)));

#define C_ 2048
#define L_ 2048
#define H_ 16
#define D_ 128
#define SIXC 12288

__device__ __forceinline__ u16 f2bf(float f) {
  union { float f; unsigned u; } v; v.f = f;
  unsigned r = v.u + 0x7FFFu + ((v.u >> 16) & 1u);
  return (u16)(r >> 16);
}
__device__ __forceinline__ float bf2f(u16 b) {
  union { unsigned u; float f; } v; v.u = ((unsigned)b) << 16; return v.f;
}

#define GLOAD_LDS16(g, l)                                            \
  __builtin_amdgcn_global_load_lds(                                  \
      (__attribute__((address_space(1))) void*)(g),                  \
      (__attribute__((address_space(3))) void*)(l), 16, 0, 0)

template <int N> __device__ __forceinline__ void wait_vmcnt() {
  if constexpr (N == 8)      asm volatile("s_waitcnt vmcnt(8)" ::: "memory");
  else if constexpr (N == 6) asm volatile("s_waitcnt vmcnt(6)" ::: "memory");
  else                       asm volatile("s_waitcnt vmcnt(0)" ::: "memory");
}

// ---------------- convert all 4 weight mats f32 -> bf16 (one launch) --------
#define NQKV 12582912
#define NPRJ 4194304
#define NFC1 16777216
#define NFC2 16777216
__global__ __launch_bounds__(256) void conv_all(
    const float* __restrict__ wqkv, const float* __restrict__ wproj,
    const float* __restrict__ wfc1, const float* __restrict__ wfc2,
    u16* __restrict__ oqkv, u16* __restrict__ oproj,
    u16* __restrict__ ofc1, u16* __restrict__ ofc2) {
  int i = (blockIdx.x * 256 + threadIdx.x) * 4;
  const float* src; u16* dst; int off;
  if (i < NQKV) { src = wqkv; dst = oqkv; off = i; }
  else if (i < NQKV + NPRJ) { src = wproj; dst = oproj; off = i - NQKV; }
  else if (i < NQKV + NPRJ + NFC1) { src = wfc1; dst = ofc1; off = i - NQKV - NPRJ; }
  else { src = wfc2; dst = ofc2; off = i - NQKV - NPRJ - NFC1; }
  float4 v = *(const float4*)&src[off];
  ushort4 o;
  o.x = f2bf(v.x); o.y = f2bf(v.y); o.z = f2bf(v.z); o.w = f2bf(v.w);
  *(ushort4*)&dst[off] = o;
}

// ---------------- prep: silu(cond), qkv bias, per-head scale, zero flag -----
__global__ __launch_bounds__(256) void prep_kernel(
    const float* __restrict__ cond, const float* __restrict__ qb,
    const float* __restrict__ vb, const float* __restrict__ sml,
    float* __restrict__ silu_cond, float* __restrict__ qkvbias,
    float* __restrict__ sm, int* __restrict__ bflag) {
  int i = blockIdx.x * 256 + threadIdx.x;
  if (i == 0) bflag[0] = 0;
  if (i < 4096) { float c = cond[i]; silu_cond[i] = c / (1.f + __expf(-c)); }
  if (i < 6144) {
    float bv = (i < 2048) ? qb[i] : ((i < 4096) ? 0.f : vb[i - 4096]);
    qkvbias[i] = bv;
  }
  if (i < 16) sm[i] = __expf(fminf(sml[i], 4.6051701859880914f)); // log(100)
}

// ---------------- attn_bias zero detect (16MB scan) -------------------------
__global__ __launch_bounds__(256) void bias_check(
    const float* __restrict__ b, int* __restrict__ flag) {
  int i = (blockIdx.x * 256 + threadIdx.x) * 4;
  float4 v = *(const float4*)&b[i];
  bool nz = (v.x != 0.f) | (v.y != 0.f) | (v.z != 0.f) | (v.w != 0.f);
  if (__any(nz) && (threadIdx.x & 63) == 0) atomicOr(flag, 1);
}

// ---------------- ada = silu(cond) @ Wada^T + bada  (one wave per row) ------
__global__ __launch_bounds__(256) void ada_gemm(
    const float* __restrict__ sc, const float* __restrict__ Wada,
    const float* __restrict__ bada, float* __restrict__ ada) {
  int gw = (blockIdx.x * 256 + threadIdx.x) >> 6;
  int lane = threadIdx.x & 63;
  int b = gw / SIXC, row = gw % SIXC;
  const float* s0 = sc + b * 2048;
  const float* w0 = Wada + (size_t)row * 2048;
  float s = 0.f;
  for (int k = lane * 4; k < 2048; k += 256) {
    float4 a = *(const float4*)&s0[k];
    float4 w = *(const float4*)&w0[k];
    s = fmaf(a.x, w.x, s); s = fmaf(a.y, w.y, s);
    s = fmaf(a.z, w.z, s); s = fmaf(a.w, w.w, s);
  }
  #pragma unroll
  for (int off = 32; off; off >>= 1) s += __shfl_xor(s, off);
  if (lane == 0) ada[(size_t)b * SIXC + row] = s + bada[row];
}

// ---------------- LN + modulate -> bf16 -------------------------------------
__global__ __launch_bounds__(256) void ln_mod(
    const float* __restrict__ x, const float* __restrict__ ada,
    u16* __restrict__ out, int soff, int shoff) {
  int r = blockIdx.x;            // row in [0,4096)
  int b = r >> 11;
  int tid = threadIdx.x;
  const float* xr = x + (size_t)r * 2048;
  int c0 = tid * 8;
  float4 u0 = *(const float4*)&xr[c0];
  float4 u1 = *(const float4*)&xr[c0 + 4];
  float v[8] = {u0.x,u0.y,u0.z,u0.w,u1.x,u1.y,u1.z,u1.w};
  float s = 0.f, s2 = 0.f;
  #pragma unroll
  for (int j = 0; j < 8; ++j) { s += v[j]; s2 = fmaf(v[j], v[j], s2); }
  int wv = tid >> 6, lane = tid & 63;
  #pragma unroll
  for (int off = 32; off; off >>= 1) { s += __shfl_xor(s, off); s2 += __shfl_xor(s2, off); }
  __shared__ float red[8];
  if (!lane) { red[wv] = s; red[4 + wv] = s2; }
  __syncthreads();
  s = red[0] + red[1] + red[2] + red[3];
  s2 = red[4] + red[5] + red[6] + red[7];
  float mean = s * (1.f / 2048.f);
  float var = s2 * (1.f / 2048.f) - mean * mean;
  float rstd = rsqrtf(var + 1e-6f);
  const float* sc = ada + (size_t)b * SIXC + soff;
  const float* sh = ada + (size_t)b * SIXC + shoff;
  u16* orow = out + (size_t)r * 2048;
  #pragma unroll
  for (int j = 0; j < 8; ++j) {
    int c = c0 + j;
    float y = (v[j] - mean) * rstd * (1.f + sc[c]) + sh[c];
    orow[c] = f2bf(y);
  }
}

// ---------------- q/k L2 normalize in place (bf16), q *= sm[h] --------------
__global__ __launch_bounds__(256) void qk_norm_bf(
    u16* __restrict__ qb, u16* __restrict__ kb, const float* __restrict__ sm) {
  int gw = (blockIdx.x * 256 + threadIdx.x) >> 6;  // [0, 131072)
  int lane = threadIdx.x & 63;
  int which = gw >> 16;         // 0: q, 1: k (65536 rows each)
  int rid = gw & 0xFFFF;
  int h = (rid >> 11) & 15;
  u16* base = (which ? kb : qb) + (size_t)rid * 128 + lane * 2;
  unsigned uu = *(const unsigned*)base;
  float v0 = bf2f((u16)(uu & 0xFFFFu));
  float v1 = bf2f((u16)(uu >> 16));
  float ss = v0 * v0 + v1 * v1;
  #pragma unroll
  for (int off = 32; off; off >>= 1) ss += __shfl_xor(ss, off);
  float rn = 1.f / fmaxf(sqrtf(ss), 1e-12f);
  if (which == 0) rn *= sm[h];
  unsigned o = (unsigned)f2bf(v0 * rn) | ((unsigned)f2bf(v1 * rn) << 16);
  *(unsigned*)base = o;
}

// -- MFMA flash attention (v5 + zero-bias fast path) -------------------------
#define PSP 68
__global__ __launch_bounds__(256) void attn_mfma(
    const u16* __restrict__ qb, const u16* __restrict__ kb,
    const u16* __restrict__ vbt, const float* __restrict__ bias,
    const int* __restrict__ bflag, u16* __restrict__ o) {
  __shared__ u16 Ks[2][64 * 128];
  __shared__ u16 Vt[2][128 * 64];
  __shared__ u16 Ps[4][16 * PSP];
  int tid = threadIdx.x;
  int w = tid >> 6, lane = tid & 63;
  int flat = blockIdx.y * gridDim.x + blockIdx.x;
  int rl = (flat & 7) * 128 + (flat >> 3);
  int bh = rl >> 5, b = bh >> 4, h = bh & 15;
  int q0 = (rl & 31) * 64;
  int lr = lane & 15, lg = lane >> 4;
  const int hasb = bflag[0];
  short8 aq[4];
  {
    const u16* qrow = qb + ((size_t)bh * L_ + q0 + w * 16 + lr) * 128 + lg * 8;
    #pragma unroll
    for (int ks = 0; ks < 4; ++ks) aq[ks] = *(const short8*)(qrow + ks * 32);
  }
  f32x4 oacc[8] = {};
  float m = -1e30f, l = 0.f;
  const float* brow = bias + (size_t)(q0 + w * 16 + lr) * L_;
  const u16* kbase = kb + (size_t)bh * L_ * 128;
  const u16* vbase = vbt + (size_t)bh * 128 * L_;
  const int kq0 = tid;
  const int vq0 = tid;

  float4 brg[4], bnr[4];
  #pragma unroll
  for (int i = 0; i < 4; ++i) {
    int q = i * 256 + kq0;
    int r = q >> 4, c = q & 15;
    GLOAD_LDS16(kbase + (size_t)r * 128 + ((c ^ (r & 7)) * 8), &Ks[0][q * 8]);
  }
  #pragma unroll
  for (int i = 0; i < 4; ++i) {
    int q = i * 256 + vq0;
    int r = q >> 3, c = q & 7;
    GLOAD_LDS16(vbase + (size_t)r * L_ + ((c ^ (r & 7)) * 8), &Vt[0][q * 8]);
  }
  #pragma unroll
  for (int kg = 0; kg < 4; ++kg) {
    if (hasb) brg[kg] = *(const float4*)&brow[kg * 16 + lg * 4];
    else { brg[kg].x = 0.f; brg[kg].y = 0.f; brg[kg].z = 0.f; brg[kg].w = 0.f; }
    bnr[kg].x = 0.f; bnr[kg].y = 0.f; bnr[kg].z = 0.f; bnr[kg].w = 0.f;
  }
  __syncthreads();

  for (int kt = 0; kt < 32; ++kt) {
    const int cur = kt & 1;
    if (kt < 31) {
      const int nxt = cur ^ 1;
      const u16* kb2 = kbase + (size_t)(kt + 1) * 64 * 128;
      #pragma unroll
      for (int i = 0; i < 4; ++i) {
        int q = i * 256 + kq0;
        int r = q >> 4, c = q & 15;
        GLOAD_LDS16(kb2 + (size_t)r * 128 + ((c ^ (r & 7)) * 8), &Ks[nxt][q * 8]);
      }
      #pragma unroll
      for (int i = 0; i < 4; ++i) {
        int q = i * 256 + vq0;
        int r = q >> 3, c = q & 7;
        GLOAD_LDS16(vbase + (size_t)r * L_ + (kt + 1) * 64 + ((c ^ (r & 7)) * 8),
                    &Vt[nxt][q * 8]);
      }
      if (hasb) {
        #pragma unroll
        for (int kg = 0; kg < 4; ++kg)
          bnr[kg] = *(const float4*)&brow[(kt + 1) * 64 + kg * 16 + lg * 4];
      }
    }
    f32x4 s[4] = {};
    __builtin_amdgcn_s_setprio(1);
    #pragma unroll
    for (int ks = 0; ks < 4; ++ks) {
      #pragma unroll
      for (int kg = 0; kg < 4; ++kg) {
        int row = kg * 16 + lr;
        short8 bk = *(const short8*)&Ks[cur][row * 128 + (((ks * 4 + lg) ^ (lr & 7)) * 8)];
        s[kg] = __builtin_amdgcn_mfma_f32_16x16x32_bf16(bk, aq[ks], s[kg], 0, 0, 0);
      }
    }
    __builtin_amdgcn_s_setprio(0);
    float p[4][4];
    #pragma unroll
    for (int kg = 0; kg < 4; ++kg) {
      p[kg][0] = s[kg][0] + brg[kg].x;
      p[kg][1] = s[kg][1] + brg[kg].y;
      p[kg][2] = s[kg][2] + brg[kg].z;
      p[kg][3] = s[kg][3] + brg[kg].w;
    }
    float tm = fmaxf(
        fmaxf(fmaxf(fmaxf(p[0][0], p[0][1]), fmaxf(p[0][2], p[0][3])),
              fmaxf(fmaxf(p[1][0], p[1][1]), fmaxf(p[1][2], p[1][3]))),
        fmaxf(fmaxf(fmaxf(p[2][0], p[2][1]), fmaxf(p[2][2], p[2][3])),
              fmaxf(fmaxf(p[3][0], p[3][1]), fmaxf(p[3][2], p[3][3]))));
    tm = fmaxf(tm, __shfl_xor(tm, 16));
    tm = fmaxf(tm, __shfl_xor(tm, 32));
    if (__any(tm > m + 8.f)) {
      float nm = fmaxf(m, tm);
      float a = __expf(m - nm);
      m = nm;
      l *= a;
      float al[4];
      #pragma unroll
      for (int j = 0; j < 4; ++j) al[j] = __shfl(a, lg * 4 + j);
      #pragma unroll
      for (int dg = 0; dg < 8; ++dg) {
        f32x4 t = oacc[dg];
        t[0] *= al[0]; t[1] *= al[1]; t[2] *= al[2]; t[3] *= al[3];
        oacc[dg] = t;
      }
    }
    float ps = 0.f;
    #pragma unroll
    for (int kg = 0; kg < 4; ++kg) {
      #pragma unroll
      for (int j = 0; j < 4; ++j) { p[kg][j] = __expf(p[kg][j] - m); ps += p[kg][j]; }
    }
    ps += __shfl_xor(ps, 16);
    ps += __shfl_xor(ps, 32);
    l += ps;
    #pragma unroll
    for (int kg = 0; kg < 4; ++kg) {
      unsigned lo = (unsigned)f2bf(p[kg][0]) | ((unsigned)f2bf(p[kg][1]) << 16);
      unsigned hi = (unsigned)f2bf(p[kg][2]) | ((unsigned)f2bf(p[kg][3]) << 16);
      uint2 w2; w2.x = lo; w2.y = hi;
      *(uint2*)&Ps[w][lr * PSP + kg * 16 + lg * 4] = w2;
    }
    __threadfence_block();
    short8 pa0 = *(const short8*)&Ps[w][lr * PSP + lg * 8];
    short8 pa1 = *(const short8*)&Ps[w][lr * PSP + 32 + lg * 8];
    __builtin_amdgcn_s_setprio(1);
    #pragma unroll
    for (int dg = 0; dg < 8; ++dg) {
      int row = dg * 16 + lr;
      short8 bv0 = *(const short8*)&Vt[cur][row * 64 + ((lg ^ (lr & 7)) * 8)];
      oacc[dg] = __builtin_amdgcn_mfma_f32_16x16x32_bf16(pa0, bv0, oacc[dg], 0, 0, 0);
      short8 bv1 = *(const short8*)&Vt[cur][row * 64 + (((4 + lg) ^ (lr & 7)) * 8)];
      oacc[dg] = __builtin_amdgcn_mfma_f32_16x16x32_bf16(pa1, bv1, oacc[dg], 0, 0, 0);
    }
    __builtin_amdgcn_s_setprio(0);
    __syncthreads();
    #pragma unroll
    for (int i = 0; i < 4; ++i) brg[i] = bnr[i];
  }
  float inv[4];
  #pragma unroll
  for (int j = 0; j < 4; ++j) inv[j] = 1.f / __shfl(l, lg * 4 + j);
  #pragma unroll
  for (int j = 0; j < 4; ++j) {
    u16* dst = &o[((size_t)(b * L_) + q0 + w * 16 + lg * 4 + j) * 2048 + h * 128 + lr];
    #pragma unroll
    for (int dg = 0; dg < 8; ++dg) dst[dg * 16] = f2bf(oacc[dg][j] * inv[j]);
  }
}

// ------ 256x256 4-phase GEMM, 8 waves (2Mx4N), BK=64 (R4/R6 config) ---------
#define RD_A(cur, mh)                                                         \
  _Pragma("unroll") for (int kk = 0; kk < 2; ++kk) {                          \
    const int col_ = (kk * 32 + lg * 8) ^ cswz;                               \
    _Pragma("unroll") for (int i = 0; i < 4; ++i)                             \
      af[i][kk] = *(const short8*)                                            \
          &As[cur][(wr * 128 + (mh) * 64 + i * 16 + lr) * 64 + col_];         \
  }
#define RD_B(cur, nh, BB)                                                     \
  _Pragma("unroll") for (int kk = 0; kk < 2; ++kk) {                          \
    const int col_ = (kk * 32 + lg * 8) ^ cswz;                               \
    _Pragma("unroll") for (int j = 0; j < 2; ++j)                             \
      BB[j][kk] = *(const short8*)                                            \
          &Bs[cur][(wc * 64 + (nh) * 32 + j * 16 + lr) * 64 + col_];          \
  }
#define MMQ(mh, nh, BB)                                                       \
  __builtin_amdgcn_s_setprio(1);                                              \
  _Pragma("unroll") for (int kk = 0; kk < 2; ++kk)                            \
  _Pragma("unroll") for (int i = 0; i < 4; ++i)                               \
  _Pragma("unroll") for (int j = 0; j < 2; ++j)                               \
    acc[(mh) * 4 + i][(nh) * 2 + j] = __builtin_amdgcn_mfma_f32_16x16x32_bf16(\
        af[i][kk], BB[j][kk], acc[(mh) * 4 + i][(nh) * 2 + j], 0, 0, 0);      \
  __builtin_amdgcn_s_setprio(0);
#define LGKM0 asm volatile("s_waitcnt lgkmcnt(0)" ::: "memory")

// EPI 0: qkv scatter; EPI 1: gelu->bf16; EPI 3: split-K bf16 partial
template <int EPI>
__global__ __launch_bounds__(512, 2) void gemm256(
    const u16* __restrict__ A, const u16* __restrict__ W,
    const float* __restrict__ bias,
    u16* __restrict__ outb,
    u16* __restrict__ p0, u16* __restrict__ p1, u16* __restrict__ p2,
    int M, int N, int K, int lda) {
  __shared__ __attribute__((aligned(16))) u16 As[2][256 * 64];
  __shared__ __attribute__((aligned(16))) u16 Bs[2][256 * 64];
  const int tid = threadIdx.x;
  int my = blockIdx.y, half = 0;
  if constexpr (EPI == 3) { half = my >> 4; my &= 15; }
  const int m0 = my * 256, n0 = blockIdx.x * 256;
  const int wv = tid >> 6, lane = tid & 63;
  const int wr = wv >> 2, wc = wv & 3;
  const int lr = lane & 15, lg = lane >> 4;
  const int sr = lane >> 3;
  const int scol = ((lane & 7) ^ sr) * 8;   // pre-swizzled global col
  const int cswz = (lr & 7) * 8;            // read-side col xor
  f32x4 acc[8][4] = {};
  const u16* Ab = A + (size_t)m0 * lda + (size_t)half * K;
  const u16* Bb = W + (size_t)n0 * lda + (size_t)half * K;
  const int nt = K >> 6;

  auto stA2 = [&](int bi, int k0, int sel) {   // 2 loads: half the A rows
    #pragma unroll
    for (int q = 0; q < 2; ++q) {
      int c = wv * 2 + q;
      int chunk = sel == 0 ? (c < 8 ? c : c + 8)      // rows 0-63,128-191
                           : (c < 8 ? c + 8 : c + 16); // rows 64-127,192-255
      int row = chunk * 8 + sr;
      GLOAD_LDS16(Ab + (size_t)row * lda + k0 + scol, &As[bi][chunk * 512]);
    }
  };
  auto stA4 = [&](int bi, int k0) {            // full A tile
    #pragma unroll
    for (int q = 0; q < 4; ++q) {
      int chunk = wv * 4 + q, row = chunk * 8 + sr;
      GLOAD_LDS16(Ab + (size_t)row * lda + k0 + scol, &As[bi][chunk * 512]);
    }
  };
  auto stB4 = [&](int bi, int k0) {            // full B tile
    #pragma unroll
    for (int q = 0; q < 4; ++q) {
      int chunk = wv * 4 + q, row = chunk * 8 + sr;
      GLOAD_LDS16(Bb + (size_t)row * lda + k0 + scol, &Bs[bi][chunk * 512]);
    }
  };

  short8 af[4][2], bfl[2][2], bfh[2][2];
  // prologue: tiles 0 and 1 fully in flight; wait tile 0
  stA4(0, 0); stB4(0, 0);
  stA4(1, 64); stB4(1, 64);
  wait_vmcnt<8>();
  __builtin_amdgcn_s_barrier();

  for (int t = 0; t < nt; ++t) {
    const int cur = t & 1;
    const int k2 = (t + 2) << 6;
    const bool st = t + 2 < nt;
    // ---- ph1: quadrant (m0, n-lo) ----
    RD_A(cur, 0); RD_B(cur, 0, bfl);
    __builtin_amdgcn_s_barrier();
    LGKM0;
    MMQ(0, 0, bfl);
    __builtin_amdgcn_s_barrier();
    // ---- ph2: quadrant (m0, n-hi); stage A rows S1 of t+2 ----
    RD_B(cur, 1, bfh);
    __builtin_amdgcn_s_barrier();
    LGKM0;
    if (st) stA2(cur, k2, 0);
    MMQ(0, 1, bfh);
    __builtin_amdgcn_s_barrier();
    // ---- ph3: quadrant (m1, n-lo); stage full B of t+2 ----
    RD_A(cur, 1);
    __builtin_amdgcn_s_barrier();
    LGKM0;
    if (st) stB4(cur, k2);
    MMQ(1, 0, bfl);
    __builtin_amdgcn_s_barrier();
    // keep VMEM/DS-writes below this rendezvous (A-S2 frees only here)
    __builtin_amdgcn_sched_barrier(0x10F);
    // ---- ph4 (merged, no reads): stage A rows S2; gate t+1 ----
    if (st) { stA2(cur, k2, 1); wait_vmcnt<8>(); }
    else if (t + 1 < nt) { wait_vmcnt<0>(); }
    MMQ(1, 1, bfh);
    __builtin_amdgcn_s_barrier();
  }

  #pragma unroll
  for (int mi = 0; mi < 8; ++mi) {
    #pragma unroll
    for (int ni = 0; ni < 4; ++ni) {
      int gcol = n0 + wc * 64 + ni * 16 + lr;
      float bv = (EPI == 3) ? 0.f : bias[gcol];
      #pragma unroll
      for (int j = 0; j < 4; ++j) {
        int grow = m0 + wr * 128 + mi * 16 + lg * 4 + j;
        float v = acc[mi][ni][j] + bv;
        if constexpr (EPI == 0) {
          int which = gcol >> 11;
          int h = (gcol >> 7) & 15;
          int d = gcol & 127;
          int b = grow >> 11, ll = grow & 2047;
          int bh = b * 16 + h;
          if (which == 0)      p0[((size_t)bh * L_ + ll) * 128 + d] = f2bf(v);
          else if (which == 1) p1[((size_t)bh * L_ + ll) * 128 + d] = f2bf(v);
          else                 p2[((size_t)bh * 128 + d) * L_ + ll] = f2bf(v);
        } else if constexpr (EPI == 1) {
          float u = 0.7978845608028654f * (v + 0.044715f * v * v * v);
          float e = __expf(2.f * u);
          float th = 1.f - 2.f / (e + 1.f);
          outb[(size_t)grow * N + gcol] = f2bf(0.5f * v * (1.f + th));
        } else {
          u16* pd = half ? p1 : p0;
          pd[(size_t)grow * N + gcol] = f2bf(v);
        }
      }
    }
  }
}

// ---- fc2 combine: out = res + (pa+pb+bias)*gamma2 --------------------------
__global__ __launch_bounds__(256) void fc2_combine(
    const u16* __restrict__ pa, const u16* __restrict__ pb,
    const float* __restrict__ bias, const float* __restrict__ res,
    const float* __restrict__ ada, float* __restrict__ out) {
  int i = (blockIdx.x * 256 + threadIdx.x) * 4;   // over 4096*2048 floats
  int col = i & 2047;
  int b = i >> 22;
  ushort4 a4 = *(const ushort4*)&pa[i];
  ushort4 b4 = *(const ushort4*)&pb[i];
  float4 r = *(const float4*)&res[i];
  const float* ad = ada + (size_t)b * SIXC + C_;
  float4 o;
  o.x = r.x + (bf2f(a4.x) + bf2f(b4.x) + bias[col])     * ad[col];
  o.y = r.y + (bf2f(a4.y) + bf2f(b4.y) + bias[col + 1]) * ad[col + 1];
  o.z = r.z + (bf2f(a4.z) + bf2f(b4.z) + bias[col + 2]) * ad[col + 2];
  o.w = r.w + (bf2f(a4.w) + bf2f(b4.w) + bias[col + 3]) * ad[col + 3];
  *(float4*)&out[i] = o;
}

// ------ 128x128 bf16 GEMM, counted-vmcnt double buffer (proj) ---------------
template <int EPI>
__global__ __launch_bounds__(256) void gemm128(
    const u16* __restrict__ A, const u16* __restrict__ W,
    const float* __restrict__ bias, const float* __restrict__ res,
    const float* __restrict__ ada, int goff,
    float* __restrict__ outf, u16* __restrict__ outb,
    int M, int N, int K) {
  __shared__ u16 As[2][128 * 64];
  __shared__ u16 Bs[2][128 * 64];
  const int tid = threadIdx.x;
  const int m0 = blockIdx.y * 128, n0 = blockIdx.x * 128;
  const int wv = tid >> 6, lane = tid & 63;
  const int wr = wv >> 1, wc = wv & 1;
  const int lr = lane & 15, lg = lane >> 4;
  const int sr = lane >> 3;
  const int scol = ((lane & 7) ^ sr) * 8;
  const int cswz = (lr & 7) * 8;
  f32x4 acc[4][4] = {};
  const u16* Ab = A + (size_t)m0 * K;
  const u16* Bb = W + (size_t)n0 * K;
  const int nt = K >> 6;
  auto stage = [&](int bi, int k0) {
    #pragma unroll
    for (int p = 0; p < 4; ++p) {
      int chunk = wv * 4 + p;
      int row = chunk * 8 + sr;
      GLOAD_LDS16(Ab + (size_t)row * K + k0 + scol, &As[bi][chunk * 512]);
      GLOAD_LDS16(Bb + (size_t)row * K + k0 + scol, &Bs[bi][chunk * 512]);
    }
  };
  stage(0, 0);
  stage(1, 64);
  for (int t = 0; t < nt; ++t) {
    const int cur = t & 1;
    if (t + 1 < nt) wait_vmcnt<8>(); else wait_vmcnt<0>();
    __builtin_amdgcn_s_barrier();
    __builtin_amdgcn_sched_barrier(0);
    #pragma unroll
    for (int kk = 0; kk < 2; ++kk) {
      short8 af[4], bfr[4];
      const int col = (kk * 32 + lg * 8) ^ cswz;
      #pragma unroll
      for (int i = 0; i < 4; ++i) {
        af[i]  = *(const short8*)&As[cur][(wr * 64 + i * 16 + lr) * 64 + col];
        bfr[i] = *(const short8*)&Bs[cur][(wc * 64 + i * 16 + lr) * 64 + col];
      }
      #pragma unroll
      for (int mi = 0; mi < 4; ++mi)
        #pragma unroll
        for (int ni = 0; ni < 4; ++ni)
          acc[mi][ni] = __builtin_amdgcn_mfma_f32_16x16x32_bf16(af[mi], bfr[ni], acc[mi][ni], 0, 0, 0);
    }
    __builtin_amdgcn_sched_barrier(0);
    asm volatile("s_waitcnt lgkmcnt(0)" ::: "memory");
    __builtin_amdgcn_s_barrier();
    __builtin_amdgcn_sched_barrier(0);
    if (t + 2 < nt) stage(cur, (t + 2) << 6);
  }
  #pragma unroll
  for (int mi = 0; mi < 4; ++mi) {
    #pragma unroll
    for (int ni = 0; ni < 4; ++ni) {
      int gcol = n0 + wc * 64 + ni * 16 + lr;
      float bv = bias[gcol];
      #pragma unroll
      for (int j = 0; j < 4; ++j) {
        int grow = m0 + wr * 64 + mi * 16 + lg * 4 + j;
        float v = acc[mi][ni][j] + bv;
        if (EPI == 1) {
          float u = 0.7978845608028654f * (v + 0.044715f * v * v * v);
          float e = __expf(2.f * u);
          float th = 1.f - 2.f / (e + 1.f);
          outb[(size_t)grow * N + gcol] = f2bf(0.5f * v * (1.f + th));
        } else {
          int b = grow >> 11;
          float g = ada[(size_t)b * SIXC + goff + gcol];
          size_t oi = (size_t)grow * N + gcol;
          outf[oi] = res[oi] + v * g;
        }
      }
    }
  }
}

// ---------------------------------------------------------------------------
extern "C" void kernel_launch(void* const* d_in, const int* in_sizes, int n_in,
                              void* d_out, int out_size, void* d_ws, size_t ws_size,
                              hipStream_t stream) {
  const float* x        = (const float*)d_in[0];
  const float* cond     = (const float*)d_in[1];
  const float* attnbias = (const float*)d_in[2];
  const float* Wqkv     = (const float*)d_in[3];
  const float* q_bias   = (const float*)d_in[4];
  const float* v_bias   = (const float*)d_in[5];
  const float* sml      = (const float*)d_in[6];
  const float* Wproj    = (const float*)d_in[7];
  const float* bproj    = (const float*)d_in[8];
  const float* Wada     = (const float*)d_in[9];
  const float* bada     = (const float*)d_in[10];
  const float* Wfc1     = (const float*)d_in[11];
  const float* bfc1     = (const float*)d_in[12];
  const float* Wfc2     = (const float*)d_in[13];
  const float* bfc2     = (const float*)d_in[14];
  float* out = (float*)d_out;
  char* ws = (char*)d_ws;
  const size_t MB = 1ull << 20;

  float* silu_cond = (float*)(ws + 0);
  float* qkvbias   = (float*)(ws + (16 << 10));
  float* smbuf     = (float*)(ws + (40 << 10));
  int*   bflag     = (int*)(ws + (44 << 10));
  float* adab      = (float*)(ws + (48 << 10));
  u16*   xob       = (u16*)(ws + 1 * MB);     // 16MB: ln1 out / attn out / ln2 out
  u16*   qbb       = (u16*)(ws + 17 * MB);    // 16MB
  u16*   kbb       = (u16*)(ws + 33 * MB);    // 16MB
  float* x1        = (float*)(ws + 17 * MB);  // 32MB f32 (aliases qbb+kbb, dead by proj)
  u16*   vbt       = (u16*)(ws + 49 * MB);    // 16MB
  u16*   hbuf      = (u16*)(ws + 49 * MB);    // 64MB (aliases vbt+wqkv+wproj, dead by fc1)
  u16*   wqkv_bf   = (u16*)(ws + 65 * MB);    // 24MB
  u16*   wproj_bf  = (u16*)(ws + 89 * MB);    // 8MB
  u16*   wfc1_bf   = (u16*)(ws + 113 * MB);   // 32MB
  u16*   wfc2_bf   = (u16*)(ws + 145 * MB);   // 32MB  (total 177MB)
  u16*   pa        = (u16*)(ws + 1 * MB);     // 16MB fc2 partial (xob dead by fc2)
  u16*   pb        = (u16*)(ws + 113 * MB);   // 16MB fc2 partial (wfc1 dead by fc2)

  conv_all<<<49152, 256, 0, stream>>>(Wqkv, Wproj, Wfc1, Wfc2,
                                      wqkv_bf, wproj_bf, wfc1_bf, wfc2_bf);
  prep_kernel<<<24, 256, 0, stream>>>(cond, q_bias, v_bias, sml, silu_cond,
                                      qkvbias, smbuf, bflag);
  bias_check<<<4096, 256, 0, stream>>>(attnbias, bflag);
  ada_gemm<<<6144, 256, 0, stream>>>(silu_cond, Wada, bada, adab);
  ln_mod<<<4096, 256, 0, stream>>>(x, adab, xob, 2 * C_, 4 * C_);
  gemm256<0><<<dim3(24, 16), 512, 0, stream>>>(xob, wqkv_bf, qkvbias,
      nullptr, qbb, kbb, vbt, 4096, 6144, 2048, 2048);
  qk_norm_bf<<<32768, 256, 0, stream>>>(qbb, kbb, smbuf);
  attn_mfma<<<dim3(32, 32), 256, 0, stream>>>(qbb, kbb, vbt, attnbias, bflag, xob);
  gemm128<2><<<dim3(16, 32), 256, 0, stream>>>(xob, wproj_bf, bproj, x, adab, 0,
      x1, nullptr, 4096, 2048, 2048);
  ln_mod<<<4096, 256, 0, stream>>>(x1, adab, xob, 3 * C_, 5 * C_);
  gemm256<1><<<dim3(32, 16), 512, 0, stream>>>(xob, wfc1_bf, bfc1,
      hbuf, nullptr, nullptr, nullptr, 4096, 8192, 2048, 2048);
  gemm256<3><<<dim3(8, 32), 512, 0, stream>>>(hbuf, wfc2_bf, bfc2,
      nullptr, pa, pb, nullptr, 4096, 2048, 4096, 8192);
  fc2_combine<<<8192, 256, 0, stream>>>(pa, pb, bfc2, x1, adab, out);
}